// Round 1
// 200.199 us; speedup vs baseline: 1.0123x; 1.0123x over previous
//
#include <hip/hip_runtime.h>
#include <hip/hip_fp16.h>

#define OUTN 16384
#define BATCH 2048
#define DIM   256

typedef _Float16 half8 __attribute__((ext_vector_type(8)));
typedef _Float16 half4 __attribute__((ext_vector_type(4)));
typedef float    floatx4 __attribute__((ext_vector_type(4)));
typedef unsigned long long u64;

__device__ __forceinline__ void gl2lds16(const void* g, void* l) {
    __builtin_amdgcn_global_load_lds(
        (const __attribute__((address_space(1))) void*)g,
        (__attribute__((address_space(3))) void*)l, 16, 0, 0);
}

// monotone float->uint map packed with column index (low 32): min(pack) = argmin
__device__ __forceinline__ u64 packkey(float v, int col) {
    unsigned u = __float_as_uint(v);
    u = (u & 0x80000000u) ? ~u : (u | 0x80000000u);
    return ((u64)u << 32) | (unsigned)col;
}
__device__ __forceinline__ float unpackval(u64 p) {
    unsigned u = (unsigned)(p >> 32);
    u = (u & 0x80000000u) ? (u & 0x7fffffffu) : ~u;
    return __uint_as_float(u);
}

// ---------------- P0 fused: [0,512) kT-transpose+colnorm halves; [512,2560) x->f16+rownorm ----
// Also emits kT32 (fp32 transposed kernel, contiguous per column) for fast exact recompute in P2.
__global__ __launch_bounds__(256) void prep_all(
        const float* __restrict__ x, const float* __restrict__ kern,
        _Float16* __restrict__ xh, float* __restrict__ rown,
        _Float16* __restrict__ kT, float* __restrict__ colnp,
        float* __restrict__ kT32) {
    int blk = blockIdx.x, t = threadIdx.x;
    if (blk < 512) {
        __shared__ float tile[64][65];
        __shared__ float npart[4][64];
        int tx = t & 63, ty = t >> 6;
        int j0 = (blk >> 1) * 64;
        int dhalf = blk & 1, dbase = dhalf * 128;
        float nrm = 0.f;
        for (int pc = 0; pc < 2; pc++) {
            int dc = dbase + pc * 64;
            __syncthreads();
            for (int it = 0; it < 16; it++) {
                int d = dc + ty + it * 4;
                float v = kern[(size_t)d * OUTN + j0 + tx];
                tile[ty + it * 4][tx] = v;
                nrm = fmaf(v, v, nrm);
            }
            __syncthreads();
            for (int c = t; c < 512; c += 256) {   // 64j x 64d f16 out, 16B chunks
                int j = c >> 3, o8 = (c & 7) * 8;
                half8 h;
                for (int u = 0; u < 8; u++) h[u] = (_Float16)tile[o8 + u][j];
                *(half8*)&kT[(size_t)(j0 + j) * DIM + dc + o8] = h;
            }
            if (kT32) {                            // 64j x 64d fp32 out, 16B chunks
                for (int c = t; c < 1024; c += 256) {
                    int j = c >> 4, o4 = (c & 15) * 4;
                    float4 f = make_float4(tile[o4][j], tile[o4 + 1][j],
                                           tile[o4 + 2][j], tile[o4 + 3][j]);
                    *(float4*)&kT32[(size_t)(j0 + j) * DIM + dc + o4] = f;
                }
            }
        }
        npart[ty][tx] = nrm;
        __syncthreads();
        if (t < 64)
            colnp[(size_t)dhalf * OUTN + j0 + t] =
                npart[0][t] + npart[1][t] + npart[2][t] + npart[3][t];
    } else {
        int b = blk - 512;                         // 2048 rows
        float v = x[b * DIM + t];
        xh[b * DIM + t] = (_Float16)v;
        float s = v * v;
        for (int off = 32; off; off >>= 1) s += __shfl_down(s, off, 64);
        __shared__ float wsum[4];
        if ((t & 63) == 0) wsum[t >> 6] = s;
        __syncthreads();
        if (t == 0) rown[b] = wsum[0] + wsum[1] + wsum[2] + wsum[3];
    }
}

// ---------------- P1: f16 MFMA GEMM (XOR-swizzled LDS) -> norms2 + top-2/128-col candidates ----
template <bool NF16>
__global__ __launch_bounds__(256) void gemm_norms(
        const _Float16* __restrict__ xh, const _Float16* __restrict__ kT,
        const float* __restrict__ rown, const float* __restrict__ colnp,
        void* __restrict__ n2out, u64* __restrict__ blockcand) {
    __shared__ __align__(16) char smem[32768];
    _Float16* As = (_Float16*)smem;                // 128 rows x 64 (16B-granules XOR-swizzled)
    _Float16* Bs = (_Float16*)(smem + 16384);
    u64* cand = (u64*)smem;                        // 128 x 32 (XOR-swizzled), reused after k-loop
    int tid  = threadIdx.x;
    int col0 = blockIdx.x * 128;
    int row0 = blockIdx.y * 128;
    int wid = tid >> 6, lane = tid & 63;
    int wr = wid >> 1, wc = wid & 1;
    int l15 = lane & 15, l4 = lane >> 4;
    int xh7 = l15 & 7;                             // XOR key for frag reads

    floatx4 acc[4][4];
    for (int i = 0; i < 4; i++)
        for (int j = 0; j < 4; j++)
            acc[i][j] = (floatx4){0.f, 0.f, 0.f, 0.f};

    for (int kt = 0; kt < 4; kt++) {
        int k0 = kt * 64;
        for (int it = 0; it < 4; it++) {
            int chunk = it * 256 + tid;            // 1024 chunks x 16B
            int r = chunk >> 3, gg = chunk & 7;
            int ksw = (gg ^ (r & 7)) * 8;          // swizzled source granule
            gl2lds16(&xh[(size_t)(row0 + r) * DIM + k0 + ksw], &As[chunk * 8]);
            gl2lds16(&kT[(size_t)(col0 + r) * DIM + k0 + ksw], &Bs[chunk * 8]);
        }
        __syncthreads();
        for (int s = 0; s < 2; s++) {
            int g = s * 4 + l4;                    // logical 16B-granule within row
            int sw = (g ^ xh7) * 8;                // physical element offset
            half8 af[4], bf[4];
            for (int i = 0; i < 4; i++)
                af[i] = *(half8*)&As[(wr * 64 + i * 16 + l15) * 64 + sw];
            for (int j = 0; j < 4; j++)
                bf[j] = *(half8*)&Bs[(wc * 64 + j * 16 + l15) * 64 + sw];
            for (int i = 0; i < 4; i++)
                for (int j = 0; j < 4; j++)
                    acc[i][j] = __builtin_amdgcn_mfma_f32_16x16x32_f16(
                        af[i], bf[j], acc[i][j], 0, 0, 0);
        }
        __syncthreads();
    }

    // epilogue: norms2 = rown + coln - 2*dot; store + per-thread per-row min of its 4 cols
    float cn[4]; int oc[4];
    int cid = wc * 16 + l15;
    for (int j = 0; j < 4; j++) {
        oc[j] = col0 + wc * 64 + j * 16 + l15;
        cn[j] = colnp[oc[j]] + colnp[OUTN + oc[j]];
    }
    for (int i = 0; i < 4; i++) {
        for (int r = 0; r < 4; r++) {
            int row_l = wr * 64 + i * 16 + l4 * 4 + r;
            int orow  = row0 + row_l;
            float rn = rown[orow];
            u64 best = ~0ull;
            for (int j = 0; j < 4; j++) {
                float val = rn + cn[j] - 2.0f * acc[i][j][r];
                size_t oi = (size_t)orow * OUTN + oc[j];
                if (NF16) ((_Float16*)n2out)[oi] = (_Float16)val;
                else      ((float*)n2out)[oi]    = val;
                u64 p = packkey(val, oc[j]);
                if (p < best) best = p;
            }
            cand[row_l * 32 + (cid ^ (row_l & 31))] = best;  // bank-conflict-free layout
        }
    }
    __syncthreads();
    if (tid < 128) {                               // per row: top-2 of 32 thread-mins
        u64 m1 = ~0ull, m2 = ~0ull;
        for (int s = 0; s < 32; s++) {
            u64 v = cand[tid * 32 + (s ^ (tid & 31))];
            if (v < m1) { m2 = m1; m1 = v; }
            else if (v < m2) { m2 = v; }
        }
        size_t base = (size_t)(row0 + tid) * 256 + blockIdx.x * 2;
        blockcand[base]     = m1;
        blockcand[base + 1] = m2;
    }
}

// ---------------- P2: candidate argmin refinement + fused gaussian finalize ----------------
template <bool NF16, bool KT32P>
__global__ __launch_bounds__(256) void refine_finalize(
        const u64* __restrict__ blockcand, const float* __restrict__ x,
        const float* __restrict__ kern, const float* __restrict__ colnp,
        const float* __restrict__ kT32, const void* __restrict__ n2in,
        float* __restrict__ out) {
    int b = blockIdx.x, t = threadIdx.x;           // 2048 x 256
    __shared__ float xrow[DIM];
    __shared__ u64 red[256];
    xrow[t] = x[b * DIM + t];
    u64 e = blockcand[(size_t)b * 256 + t];
    red[t] = e;
    __syncthreads();
    for (int off = 128; off; off >>= 1) {
        if (t < off) { u64 o = red[t + off]; if (o < red[t]) red[t] = o; }
        __syncthreads();
    }
    float minv = unpackval(red[0]);
    __syncthreads();

    // exact fp32 recompute of candidates within delta of approx min
    float ve = unpackval(e);
    u64 p = ~0ull;
    if (ve <= minv + 0.125f) {
        int j = (int)(e & 0xffffffffu);
        float dot = 0.f;
        if (KT32P) {                               // contiguous fp32 column: 64 x float4
            const float4* kc = (const float4*)&kT32[(size_t)j * DIM];
            for (int d4 = 0; d4 < DIM / 4; d4++) {
                float4 kv = kc[d4];
                dot = fmaf(xrow[d4 * 4 + 0], kv.x, dot);
                dot = fmaf(xrow[d4 * 4 + 1], kv.y, dot);
                dot = fmaf(xrow[d4 * 4 + 2], kv.z, dot);
                dot = fmaf(xrow[d4 * 4 + 3], kv.w, dot);
            }
        } else {                                   // fallback: strided original layout
            for (int d = 0; d < DIM; d++)
                dot = fmaf(xrow[d], kern[(size_t)d * OUTN + j], dot);
        }
        p = packkey((colnp[j] + colnp[OUTN + j]) - 2.0f * dot, j);  // row-const dropped
    }
    red[t] = p;
    __syncthreads();
    for (int off = 128; off; off >>= 1) {
        if (t < off) { u64 o = red[t + off]; if (o < red[t]) red[t] = o; }
        __syncthreads();
    }
    int w = (int)(red[0] & 0xffffffffu);
    int wrr = w >> 7, wcc = w & 127;

    const _Float16* r16 = (const _Float16*)n2in + (size_t)b * OUTN;
    const float*    r32 = (const float*)n2in    + (size_t)b * OUTN;
    float* rowp = out + (size_t)b * OUTN;

    // per-thread column geometry is loop-invariant: c0 = (t&31)*4, row = it*8 + (t>>5)
    int c0 = (t & 31) * 4, rb = t >> 5;
    int dc0 = c0 - wcc;
    int q0 = dc0 * dc0, q1 = (dc0 + 1) * (dc0 + 1),
        q2 = (dc0 + 2) * (dc0 + 2), q3 = (dc0 + 3) * (dc0 + 3);
    int qmin = min(min(q0, q1), min(q2, q3));
    float ec0 = __expf(-0.125f * (float)q0), ec1 = __expf(-0.125f * (float)q1),
          ec2 = __expf(-0.125f * (float)q2), ec3 = __expf(-0.125f * (float)q3);

    for (int it = 0; it < 16; it++) {
        int idx4 = it * 256 + t;
        int r = it * 8 + rb;
        int dr = r - wrr, drsq = dr * dr;
        float4 res = make_float4(0.f, 0.f, 0.f, 0.f);
        if (drsq + qmin <= 720) {                  // any of this thread's 4 cols in window
            float va, vb, vc, vd;
            if (NF16) {
                half4 h = *(const half4*)&r16[idx4 * 4];
                va = (float)h[0]; vb = (float)h[1]; vc = (float)h[2]; vd = (float)h[3];
            } else {
                float4 f = ((const float4*)r32)[idx4];
                va = f.x; vb = f.y; vc = f.z; vd = f.w;
            }
            float er = __expf(-0.125f * (float)drsq);
            if (drsq + q0 <= 720) res.x = er * ec0 * fmaxf(va, 0.f);
            if (drsq + q1 <= 720) res.y = er * ec1 * fmaxf(vb, 0.f);
            if (drsq + q2 <= 720) res.z = er * ec2 * fmaxf(vc, 0.f);
            if (drsq + q3 <= 720) res.w = er * ec3 * fmaxf(vd, 0.f);
        }
        ((float4*)rowp)[idx4] = res;
    }
}

extern "C" void kernel_launch(void* const* d_in, const int* in_sizes, int n_in,
                              void* d_out, int out_size, void* d_ws, size_t ws_size,
                              hipStream_t stream) {
    const float* x    = (const float*)d_in[0];   // (2048, 256) fp32
    const float* kern = (const float*)d_in[1];   // (256, 16384) fp32
    float* out = (float*)d_out;                  // (2048, 16384) fp32
    char* ws = (char*)d_ws;

    // ws: xh 1MB | kT 8MB | colnp 128KB | rown 8KB | blockcand 4MB | n2h 64MB | kT32 16MB
    _Float16* xh   = (_Float16*)(ws);
    _Float16* kT   = (_Float16*)(ws + (1u << 20));
    float*   colnp = (float*)(ws + (9u << 20));
    float*   rown  = (float*)(ws + (9u << 20) + (128u << 10));
    u64* blockcand = (u64*)(ws + (10u << 20));
    void*    n2h   = (void*)(ws + (14u << 20));
    bool f16path  = ws_size >= ((size_t)78 << 20);
    bool kt32path = ws_size >= ((size_t)94 << 20);
    float* kT32 = kt32path ? (float*)(ws + (78u << 20)) : nullptr;

    prep_all<<<2560, 256, 0, stream>>>(x, kern, xh, rown, kT, colnp, kT32);
    if (f16path) {
        gemm_norms<true><<<dim3(OUTN / 128, BATCH / 128), 256, 0, stream>>>(
            xh, kT, rown, colnp, n2h, blockcand);
        if (kt32path)
            refine_finalize<true, true><<<BATCH, 256, 0, stream>>>(
                blockcand, x, kern, colnp, kT32, n2h, out);
        else
            refine_finalize<true, false><<<BATCH, 256, 0, stream>>>(
                blockcand, x, kern, colnp, nullptr, n2h, out);
    } else {
        gemm_norms<false><<<dim3(OUTN / 128, BATCH / 128), 256, 0, stream>>>(
            xh, kT, rown, colnp, (void*)out, blockcand);
        refine_finalize<false, false><<<BATCH, 256, 0, stream>>>(
            blockcand, x, kern, colnp, nullptr, (const void*)out, out);
    }
}